// Round 2
// baseline (479.707 us; speedup 1.0000x reference)
//
#include <hip/hip_runtime.h>
#include <hip/hip_fp16.h>

typedef _Float16 half4v __attribute__((ext_vector_type(4)));
typedef _Float16 half8v __attribute__((ext_vector_type(8)));
typedef float floatx4 __attribute__((ext_vector_type(4)));

#define GLOBAL_AS __attribute__((address_space(1)))
#define LDS_AS __attribute__((address_space(3)))

// async 16B/lane global->LDS DMA; lds dest = wave-uniform base + lane*16
__device__ __forceinline__ void async_copy16(const _Float16* g, _Float16* l) {
    __builtin_amdgcn_global_load_lds((const GLOBAL_AS unsigned int*)g,
                                     (LDS_AS unsigned int*)l, 16, 0, 0);
}

// ---------------- convert f32 -> f16, two tensors in one launch ----------------
__global__ __launch_bounds__(256) void k_f32_to_f16_2(const float* __restrict__ a,
                                                      _Float16* __restrict__ oa, int na,
                                                      const float* __restrict__ b,
                                                      _Float16* __restrict__ ob, int nb) {
    int i = (blockIdx.x * 256 + threadIdx.x) * 4;
    const float* src;
    _Float16* dst;
    if (i < na) {
        src = a + i; dst = oa + i;
    } else {
        int j = i - na;
        if (j >= nb) return;
        src = b + j; dst = ob + j;
    }
    float4 v = *(const float4*)src;
    half4v h;
    h[0] = (_Float16)v.x; h[1] = (_Float16)v.y; h[2] = (_Float16)v.z; h[3] = (_Float16)v.w;
    *(half4v*)dst = h;
}

// ------------- transpose + convert: in[R][C] f32 -> out[C][R] f16 -------------
__global__ __launch_bounds__(256) void k_transpose_f16(const float* __restrict__ in,
                                                       _Float16* __restrict__ out,
                                                       int R, int C) {
    __shared__ float tile[32][33];
    int bc = blockIdx.x * 32;
    int br = blockIdx.y * 32;
    int tx = threadIdx.x & 31, ty = threadIdx.x >> 5;  // 32x8
#pragma unroll
    for (int i = 0; i < 32; i += 8)
        tile[ty + i][tx] = in[(size_t)(br + ty + i) * C + bc + tx];
    __syncthreads();
#pragma unroll
    for (int i = 0; i < 32; i += 8)
        out[(size_t)(bc + ty + i) * R + br + tx] = (_Float16)tile[tx][ty + i];
}

// ---------------- pack mask int32 [4096][8192] -> bits [4096][256 u32] ----------------
// Fully coalesced int4 reads; nibbles assembled to words via LDS.
__global__ __launch_bounds__(256) void k_pack_mask(const int* __restrict__ mask,
                                                   unsigned* __restrict__ mb) {
    __shared__ unsigned nib[256];
    const int* row = mask + (size_t)blockIdx.x * 8192;
    unsigned* orow = mb + (size_t)blockIdx.x * 256;
    const int tid = threadIdx.x;
#pragma unroll
    for (int pass = 0; pass < 8; ++pass) {
        int4 v = *(const int4*)(row + pass * 1024 + tid * 4);
        unsigned nb = (unsigned)(v.x > 0) | ((unsigned)(v.y > 0) << 1) |
                      ((unsigned)(v.z > 0) << 2) | ((unsigned)(v.w > 0) << 3);
        nib[tid] = nb;
        __syncthreads();
        if (tid < 32) {
            unsigned w = 0;
#pragma unroll
            for (int t = 0; t < 8; ++t) w |= nib[tid * 8 + t] << (t * 4);
            orow[pass * 32 + tid] = w;
        }
        __syncthreads();
    }
}

// ---------------- NT GEMM: C[M,N] = scale * A[M,K] @ B[N,K]^T ----------------
// 128x128 tile, BK=64, 256 threads = 4 waves (2x2 of 64x64), mfma_f32_16x16x32_f16.
// global_load_lds width=16 staging; XOR chunk swizzle (slot = chunk ^ (row&7))
// kills fragment-read bank conflicts. Used for the two projection GEMMs.
__global__ __launch_bounds__(256) void k_gemm_nt(const _Float16* __restrict__ A,
                                                 const _Float16* __restrict__ B,
                                                 _Float16* __restrict__ C,
                                                 int M, int N, int K, float scale) {
    __shared__ __align__(16) _Float16 As[128 * 64];
    __shared__ __align__(16) _Float16 Bs[128 * 64];
    const int tid  = threadIdx.x;
    const int lane = tid & 63;
    const int wave = tid >> 6;
    const int wm   = (wave >> 1) * 64;
    const int wn   = (wave & 1) * 64;
    const int quad = lane >> 4;
    const int lr   = lane & 15;
    const long m0 = (long)blockIdx.y * 128;
    const long n0 = (long)blockIdx.x * 128;

    floatx4 acc[4][4] = {};

    const int rl = lane >> 3;
    const int gc = (lane & 7) ^ rl;
    const long arow = m0 + wave * 32 + rl;
    const long brow = n0 + wave * 32 + rl;

    for (int kt = 0; kt < K; kt += 64) {
        const _Float16* Ap = A + arow * (long)K + kt + gc * 8;
        const _Float16* Bp = B + brow * (long)K + kt + gc * 8;
        _Float16* Al = &As[(wave * 32) * 64];
        _Float16* Bl = &Bs[(wave * 32) * 64];
#pragma unroll
        for (int i = 0; i < 4; ++i) {
            async_copy16(Ap + (long)(i * 8) * K, Al + i * 8 * 64);
            async_copy16(Bp + (long)(i * 8) * K, Bl + i * 8 * 64);
        }
        __syncthreads();

#pragma unroll
        for (int kk = 0; kk < 64; kk += 32) {
            half8v af[4], bf[4];
            const int cg = (kk >> 3) + quad;
            const int sl = (cg ^ (lr & 7)) * 8;
#pragma unroll
            for (int i = 0; i < 4; ++i)
                af[i] = *(const half8v*)&As[(wm + i * 16 + lr) * 64 + sl];
#pragma unroll
            for (int j = 0; j < 4; ++j)
                bf[j] = *(const half8v*)&Bs[(wn + j * 16 + lr) * 64 + sl];
#pragma unroll
            for (int i = 0; i < 4; ++i)
#pragma unroll
                for (int j = 0; j < 4; ++j)
                    acc[i][j] = __builtin_amdgcn_mfma_f32_16x16x32_f16(af[i], bf[j], acc[i][j], 0, 0, 0);
        }
        __syncthreads();
    }

    // epilogue: C/D layout col = lane&15, row = quad*4 + reg  [m89/m91]
#pragma unroll
    for (int i = 0; i < 4; ++i) {
        long rbase = m0 + wm + i * 16 + quad * 4;
#pragma unroll
        for (int j = 0; j < 4; ++j) {
            long col = n0 + wn + j * 16 + lr;
#pragma unroll
            for (int r = 0; r < 4; ++r)
                C[(rbase + r) * (long)N + col] = (_Float16)(acc[i][j][r] * scale);
        }
    }
}

// ---------------- fused flash attention core ----------------
// grid (32 q-tiles, 8 N-splits), 512 threads = 8 waves.
// Per block: Q-tile 128 rows; loop 8 key-tiles of 128 within split's 1024-range.
//   S-phase: S[128x128] = qk @ keys^T (K=512, 8 k-steps, DMA-staged As/Bs,
//            same swizzle as k_gemm_nt). Waves 2(q-half) x 4(n-quarter), S acc[4][2].
//   softmax: mask from packed bits (broadcast u32 loads, L2-resident);
//            row max/sum: in-thread over j, shfl over lr (16-lane group),
//            cross-wave (4 waves share rows) via redbuf LDS. Online rescale of O.
//   P -> Ps LDS f16, chunk-swizzled identically to As, so PV A-reads are the
//            standard conflict-free fragment reads.
//   PV: O[128x256] += P @ V; waves 2(q-half) x 4(dv-quarter), O acc[4][4];
//            B-fragments read DIRECTLY from global yT (4 MB, L2-resident).
// Output: un-normalized O partials (f32) + per-row m,l; combined by k_combine.
__global__ __launch_bounds__(512) void k_flash(const _Float16* __restrict__ Qk,
                                               const _Float16* __restrict__ Keys,
                                               const _Float16* __restrict__ Vt,
                                               const unsigned* __restrict__ Mb,
                                               float* __restrict__ Opart,
                                               float* __restrict__ Mpart,
                                               float* __restrict__ Lpart) {
    __shared__ __align__(16) _Float16 As[128 * 64];
    __shared__ __align__(16) _Float16 Bs[128 * 64];
    __shared__ __align__(16) _Float16 Ps[2][128 * 64];
    __shared__ float redbuf[8][64];

    const int tid  = threadIdx.x;
    const int lane = tid & 63;
    const int wave = tid >> 6;          // 0..7
    const int quad = lane >> 4;
    const int lr   = lane & 15;
    const int wm2  = (wave >> 2) * 64;  // q-half
    const int wn2  = (wave & 3) * 32;   // n-quarter (S phase)
    const int dvo  = (wave & 3) * 64;   // dv-quarter (PV phase)
    const int wg4  = (wave >> 2) * 4;   // first of the 4 waves sharing my q-rows
    const long q0  = (long)blockIdx.x * 128;
    const long n0beg = (long)blockIdx.y * 1024;

    floatx4 o[4][4] = {};
    float m_[4][4], l_[4][4];
#pragma unroll
    for (int i = 0; i < 4; ++i)
#pragma unroll
        for (int r = 0; r < 4; ++r) { m_[i][r] = -1.0e30f; l_[i][r] = 0.f; }

    // stager geometry: each wave stages 16 rows (2 DMAs) of As and Bs
    const int rl = lane >> 3;
    const int gc = (lane & 7) ^ rl;
    const long arow = q0 + wave * 16 + rl;

    for (int nt = 0; nt < 8; ++nt) {
        const long n0 = n0beg + nt * 128;
        floatx4 s[4][2] = {};
        // ---- S = qk @ keys^T ----
        for (int kt = 0; kt < 512; kt += 64) {
            const _Float16* Ap = Qk + arow * 512 + kt + gc * 8;
            const _Float16* Bp = Keys + (n0 + wave * 16 + rl) * 512 + kt + gc * 8;
            _Float16* Al = &As[(wave * 16) * 64];
            _Float16* Bl = &Bs[(wave * 16) * 64];
#pragma unroll
            for (int i = 0; i < 2; ++i) {
                async_copy16(Ap + (long)(i * 8) * 512, Al + i * 8 * 64);
                async_copy16(Bp + (long)(i * 8) * 512, Bl + i * 8 * 64);
            }
            __syncthreads();
#pragma unroll
            for (int kk = 0; kk < 64; kk += 32) {
                const int cg = (kk >> 3) + quad;
                const int sl = (cg ^ (lr & 7)) * 8;
                half8v af[4], bf[2];
#pragma unroll
                for (int i = 0; i < 4; ++i)
                    af[i] = *(const half8v*)&As[(wm2 + i * 16 + lr) * 64 + sl];
#pragma unroll
                for (int j = 0; j < 2; ++j)
                    bf[j] = *(const half8v*)&Bs[(wn2 + j * 16 + lr) * 64 + sl];
#pragma unroll
                for (int i = 0; i < 4; ++i)
#pragma unroll
                    for (int j = 0; j < 2; ++j)
                        s[i][j] = __builtin_amdgcn_mfma_f32_16x16x32_f16(af[i], bf[j], s[i][j], 0, 0, 0);
            }
            __syncthreads();
        }

        // ---- masked online softmax ----
        // thread owns rows tl = wm2 + i*16 + quad*4 + r (16 rows), cols wn2 + j*16 + lr
        float sv[4][2][4];
        unsigned wbit[4][4];
        float tmax[4][4];
#pragma unroll
        for (int i = 0; i < 4; ++i)
#pragma unroll
            for (int r = 0; r < 4; ++r) {
                const int tl = wm2 + i * 16 + quad * 4 + r;
                const unsigned w = Mb[(size_t)(q0 + tl) * 256 + (size_t)((n0 + wn2) >> 5)];
                wbit[i][r] = w;
                float tm = -1.0e30f;
#pragma unroll
                for (int j = 0; j < 2; ++j) {
                    const unsigned b = (w >> (j * 16 + lr)) & 1u;
                    const float val = b ? s[i][j][r] : -1.0e30f;
                    sv[i][j][r] = val;
                    tm = fmaxf(tm, val);
                }
#pragma unroll
                for (int off = 1; off < 16; off <<= 1)
                    tm = fmaxf(tm, __shfl_xor(tm, off, 64));
                tmax[i][r] = tm;
            }
        if (lr == 0) {
#pragma unroll
            for (int i = 0; i < 4; ++i)
#pragma unroll
                for (int r = 0; r < 4; ++r)
                    redbuf[wave][i * 16 + quad * 4 + r] = tmax[i][r];
        }
        __syncthreads();
#pragma unroll
        for (int i = 0; i < 4; ++i)
#pragma unroll
            for (int r = 0; r < 4; ++r) {
                const int rr = i * 16 + quad * 4 + r;
                float t = fmaxf(fmaxf(redbuf[wg4][rr], redbuf[wg4 + 1][rr]),
                                fmaxf(redbuf[wg4 + 2][rr], redbuf[wg4 + 3][rr]));
                const float mn = fmaxf(m_[i][r], t);
                const float f  = __expf(m_[i][r] - mn);   // ==1 when unchanged
                m_[i][r] = mn;
                l_[i][r] *= f;
#pragma unroll
                for (int jv = 0; jv < 4; ++jv) o[i][jv][r] *= f;
            }
        __syncthreads();   // redbuf reads done before sum phase reuses it

        // ---- P = gated exp(S - m) -> Ps (chunk-swizzled), partial row sums ----
        const int ktile = wn2 >> 6;
        float psum[4][4];
#pragma unroll
        for (int i = 0; i < 4; ++i)
#pragma unroll
            for (int r = 0; r < 4; ++r) {
                const int tl = wm2 + i * 16 + quad * 4 + r;
                const unsigned w = wbit[i][r];
                float ps = 0.f;
#pragma unroll
                for (int j = 0; j < 2; ++j) {
                    const unsigned b = (w >> (j * 16 + lr)) & 1u;
                    const float e = b ? __expf(sv[i][j][r] - m_[i][r]) : 0.f;
                    const int col  = wn2 + j * 16 + lr;
                    const int slot = (((col & 63) >> 3) ^ (tl & 7));
                    Ps[ktile][tl * 64 + slot * 8 + (col & 7)] = (_Float16)e;
                    ps += e;
                }
#pragma unroll
                for (int off = 1; off < 16; off <<= 1) ps += __shfl_xor(ps, off, 64);
                psum[i][r] = ps;
            }
        if (lr == 0) {
#pragma unroll
            for (int i = 0; i < 4; ++i)
#pragma unroll
                for (int r = 0; r < 4; ++r)
                    redbuf[wave][i * 16 + quad * 4 + r] = psum[i][r];
        }
        __syncthreads();   // covers Ps writes AND redbuf sum writes
#pragma unroll
        for (int i = 0; i < 4; ++i)
#pragma unroll
            for (int r = 0; r < 4; ++r) {
                const int rr = i * 16 + quad * 4 + r;
                l_[i][r] += redbuf[wg4][rr] + redbuf[wg4 + 1][rr] +
                            redbuf[wg4 + 2][rr] + redbuf[wg4 + 3][rr];
            }

        // ---- O += P @ V (B-fragments direct from global yT, L2-resident) ----
#pragma unroll
        for (int kp = 0; kp < 2; ++kp) {
#pragma unroll
            for (int kk = 0; kk < 64; kk += 32) {
                const int cg = (kk >> 3) + quad;
                const int sl = (cg ^ (lr & 7)) * 8;
                half8v af[4], bf[4];
#pragma unroll
                for (int i = 0; i < 4; ++i)
                    af[i] = *(const half8v*)&Ps[kp][(wm2 + i * 16 + lr) * 64 + sl];
#pragma unroll
                for (int j = 0; j < 4; ++j)
                    bf[j] = *(const half8v*)(Vt + (size_t)(dvo + j * 16 + lr) * 8192 +
                                             n0 + kp * 64 + kk + quad * 8);
#pragma unroll
                for (int i = 0; i < 4; ++i)
#pragma unroll
                    for (int j = 0; j < 4; ++j)
                        o[i][j] = __builtin_amdgcn_mfma_f32_16x16x32_f16(af[i], bf[j], o[i][j], 0, 0, 0);
            }
        }
        // next iter's As/Bs DMA only touches buffers dead since the S-phase
        // barrier; Ps/redbuf rewrites are >=2 barriers downstream. Safe.
    }

    // ---- epilogue: un-normalized partials ----
    const size_t obase = (size_t)blockIdx.y * 4096 + (size_t)q0;
#pragma unroll
    for (int i = 0; i < 4; ++i)
#pragma unroll
        for (int r = 0; r < 4; ++r) {
            const int row = wm2 + i * 16 + quad * 4 + r;
#pragma unroll
            for (int j = 0; j < 4; ++j) {
                const int col = dvo + j * 16 + lr;
                Opart[(obase + row) * 256 + col] = o[i][j][r];
            }
        }
    if (lr == 0 && (wave & 3) == 0) {
#pragma unroll
        for (int i = 0; i < 4; ++i)
#pragma unroll
            for (int r = 0; r < 4; ++r) {
                const int row = wm2 + i * 16 + quad * 4 + r;
                Mpart[obase + row] = m_[i][r];
                Lpart[obase + row] = l_[i][r];
            }
    }
}

// ---------------- combine 8 split partials -> normalized output ----------------
__global__ __launch_bounds__(256) void k_combine(const float* __restrict__ Opart,
                                                 const float* __restrict__ Mpart,
                                                 const float* __restrict__ Lpart,
                                                 float* __restrict__ out) {
    const int q  = blockIdx.x;
    const int dv = threadIdx.x;
    float ms[8];
    float M = -1.0e30f;
#pragma unroll
    for (int s = 0; s < 8; ++s) {
        ms[s] = Mpart[s * 4096 + q];
        M = fmaxf(M, ms[s]);
    }
    float L = 0.f, acc = 0.f;
#pragma unroll
    for (int s = 0; s < 8; ++s) {
        const float w = __expf(ms[s] - M);
        L += Lpart[s * 4096 + q] * w;
        acc += Opart[((size_t)s * 4096 + q) * 256 + dv] * w;
    }
    out[(size_t)q * 256 + dv] = (L > 0.f) ? acc / L : 0.f;
}

extern "C" void kernel_launch(void* const* d_in, const int* in_sizes, int n_in,
                              void* d_out, int out_size, void* d_ws, size_t ws_size,
                              hipStream_t stream) {
    const float* search_x = (const float*)d_in[0];  // [8192,1024]
    const float* search_y = (const float*)d_in[1];  // [8192,256]
    const float* query_x  = (const float*)d_in[2];  // [4096,1024]
    const int*   mask     = (const int*)d_in[3];    // [4096,8192]
    const float* Wk       = (const float*)d_in[4];  // [1024,512]
    const float* Wq       = (const float*)d_in[5];  // [1024,512]
    (void)in_sizes; (void)n_in; (void)ws_size; (void)out_size;

    char* p = (char*)d_ws;
    _Float16* xh    = (_Float16*)p; p += (size_t)8192 * 1024 * 2;  // x f16
    _Float16* qh    = (_Float16*)p; p += (size_t)4096 * 1024 * 2;  // q f16
    _Float16* wkT   = (_Float16*)p; p += (size_t)512 * 1024 * 2;   // Wk^T f16
    _Float16* wqT   = (_Float16*)p; p += (size_t)512 * 1024 * 2;   // Wq^T f16
    _Float16* yT    = (_Float16*)p; p += (size_t)256 * 8192 * 2;   // y^T f16
    _Float16* keys  = (_Float16*)p; p += (size_t)8192 * 512 * 2;   // keys f16
    _Float16* qk    = (_Float16*)p; p += (size_t)4096 * 512 * 2;   // qk f16 (pre-scaled)
    unsigned* mbits = (unsigned*)p; p += (size_t)4096 * 256 * 4;   // packed mask bits
    float*    Opart = (float*)p;    p += (size_t)8 * 4096 * 256 * 4;
    float*    Mpart = (float*)p;    p += (size_t)8 * 4096 * 4;
    float*    Lpart = (float*)p;    p += (size_t)8 * 4096 * 4;

    // converts + transposes + mask pack
    k_f32_to_f16_2<<<12288, 256, 0, stream>>>(search_x, xh, 8192 * 1024,
                                              query_x, qh, 4096 * 1024);
    k_transpose_f16<<<dim3(16, 32), 256, 0, stream>>>(Wk, wkT, 1024, 512);
    k_transpose_f16<<<dim3(16, 32), 256, 0, stream>>>(Wq, wqT, 1024, 512);
    k_transpose_f16<<<dim3(8, 256), 256, 0, stream>>>(search_y, yT, 8192, 256);
    k_pack_mask<<<4096, 256, 0, stream>>>(mask, mbits);

    // keys = x @ Wk   (M=8192,N=512,K=1024)
    k_gemm_nt<<<dim3(4, 64), 256, 0, stream>>>(xh, wkT, keys, 8192, 512, 1024, 1.0f);
    // qk = (q @ Wq) / sqrt(512)  -- scale folded here
    k_gemm_nt<<<dim3(4, 32), 256, 0, stream>>>(qh, wqT, qk, 4096, 512, 1024,
                                               0.04419417382415922f);
    // fused logits+softmax+PV, split-N=8
    k_flash<<<dim3(32, 8), 512, 0, stream>>>(qk, keys, yT, mbits, Opart, Mpart, Lpart);
    // merge splits
    k_combine<<<4096, 256, 0, stream>>>(Opart, Mpart, Lpart, (float*)d_out);
}

// Round 3
// 392.099 us; speedup vs baseline: 1.2234x; 1.2234x over previous
//
#include <hip/hip_runtime.h>
#include <hip/hip_fp16.h>

typedef _Float16 half4v __attribute__((ext_vector_type(4)));
typedef _Float16 half8v __attribute__((ext_vector_type(8)));
typedef float floatx4 __attribute__((ext_vector_type(4)));

#define GLOBAL_AS __attribute__((address_space(1)))
#define LDS_AS __attribute__((address_space(3)))

// async 16B/lane global->LDS DMA; lds dest = wave-uniform base + lane*16
__device__ __forceinline__ void async_copy16(const _Float16* g, _Float16* l) {
    __builtin_amdgcn_global_load_lds((const GLOBAL_AS unsigned int*)g,
                                     (LDS_AS unsigned int*)l, 16, 0, 0);
}

// ---------------- convert f32 -> f16, two tensors in one launch ----------------
__global__ __launch_bounds__(256) void k_f32_to_f16_2(const float* __restrict__ a,
                                                      _Float16* __restrict__ oa, int na,
                                                      const float* __restrict__ b,
                                                      _Float16* __restrict__ ob, int nb) {
    int i = (blockIdx.x * 256 + threadIdx.x) * 4;
    const float* src;
    _Float16* dst;
    if (i < na) {
        src = a + i; dst = oa + i;
    } else {
        int j = i - na;
        if (j >= nb) return;
        src = b + j; dst = ob + j;
    }
    float4 v = *(const float4*)src;
    half4v h;
    h[0] = (_Float16)v.x; h[1] = (_Float16)v.y; h[2] = (_Float16)v.z; h[3] = (_Float16)v.w;
    *(half4v*)dst = h;
}

// ------------- transpose + convert: in[R][C] f32 -> out[C][R] f16 -------------
__global__ __launch_bounds__(256) void k_transpose_f16(const float* __restrict__ in,
                                                       _Float16* __restrict__ out,
                                                       int R, int C) {
    __shared__ float tile[32][33];
    int bc = blockIdx.x * 32;
    int br = blockIdx.y * 32;
    int tx = threadIdx.x & 31, ty = threadIdx.x >> 5;  // 32x8
#pragma unroll
    for (int i = 0; i < 32; i += 8)
        tile[ty + i][tx] = in[(size_t)(br + ty + i) * C + bc + tx];
    __syncthreads();
#pragma unroll
    for (int i = 0; i < 32; i += 8)
        out[(size_t)(bc + ty + i) * R + br + tx] = (_Float16)tile[tx][ty + i];
}

// ---------------- zero-fill f32 buffer (for atomic accumulation) ----------------
__global__ __launch_bounds__(256) void k_zero_f32(float* __restrict__ p, int n) {
    int i = (blockIdx.x * 256 + threadIdx.x) * 4;
    if (i >= n) return;
    *(float4*)(p + i) = make_float4(0.f, 0.f, 0.f, 0.f);
}

// ---------------- NT GEMM: C[M,N] = scale * A[M,K] @ B[N,K]^T ----------------
// 128x128 tile, BK=64, 256 threads = 4 waves (2x2 of 64x64), mfma_f32_16x16x32_f16.
// global_load_lds width=16 staging; XOR chunk swizzle (LDS slot (row,c) holds
// global chunk (row, c^(row&7))) kills fragment-read bank conflicts (proven,
// SQ_LDS_BANK_CONFLICT==0). T1 XCD-aware block swizzle for L2 locality
// (requires gridDim.x*gridDim.y % 8 == 0 -- true for all launches here).
// OUT_MODE 0: f16 store (scaled).
// OUT_MODE 1: f32 atomic-add into C (split-K over blockIdx.z; C pre-zeroed).
template <int OUT_MODE>
__global__ __launch_bounds__(256) void k_gemm_nt(const _Float16* __restrict__ A,
                                                 const _Float16* __restrict__ B,
                                                 void* __restrict__ C,
                                                 int M, int N, int K, int kChunk,
                                                 float scale) {
    __shared__ __align__(16) _Float16 As[128 * 64];
    __shared__ __align__(16) _Float16 Bs[128 * 64];
    const int tid  = threadIdx.x;
    const int lane = tid & 63;
    const int wave = tid >> 6;
    const int wm   = (wave >> 1) * 64;
    const int wn   = (wave & 1) * 64;
    const int quad = lane >> 4;
    const int lr   = lane & 15;

    // T1: XCD-aware swizzle of the (x,y) block plane. nwg % 8 == 0 guaranteed.
    const int nx  = gridDim.x;
    const int nwg = nx * gridDim.y;
    int id = blockIdx.y * nx + blockIdx.x;
    id = (id & 7) * (nwg >> 3) + (id >> 3);
    const int bx = id % nx;
    const int by = id / nx;

    const long m0 = (long)by * 128;
    const long n0 = (long)bx * 128;
    const int kBegin = blockIdx.z * kChunk;
    const int kEnd   = kBegin + kChunk;

    floatx4 acc[4][4] = {};

    // stager geometry (per lane, i-independent)
    const int rl = lane >> 3;                       // row offset within 8-row group
    const int gc = (lane & 7) ^ rl;                 // swizzled global chunk
    const long arow = m0 + wave * 32 + rl;          // + i*8
    const long brow = n0 + wave * 32 + rl;

    for (int kt = kBegin; kt < kEnd; kt += 64) {
        const _Float16* Ap = A + arow * (long)K + kt + gc * 8;
        const _Float16* Bp = B + brow * (long)K + kt + gc * 8;
        _Float16* Al = &As[(wave * 32) * 64];
        _Float16* Bl = &Bs[(wave * 32) * 64];
#pragma unroll
        for (int i = 0; i < 4; ++i) {
            async_copy16(Ap + (long)(i * 8) * K, Al + i * 8 * 64);
            async_copy16(Bp + (long)(i * 8) * K, Bl + i * 8 * 64);
        }
        __syncthreads();  // compiler inserts vmcnt(0) drain before barrier

#pragma unroll
        for (int kk = 0; kk < 64; kk += 32) {
            half8v af[4], bf[4];
            const int cg = (kk >> 3) + quad;        // global chunk index 0..7
            const int sl = (cg ^ (lr & 7)) * 8;     // swizzled slot offset (halves)
#pragma unroll
            for (int i = 0; i < 4; ++i)
                af[i] = *(const half8v*)&As[(wm + i * 16 + lr) * 64 + sl];
#pragma unroll
            for (int j = 0; j < 4; ++j)
                bf[j] = *(const half8v*)&Bs[(wn + j * 16 + lr) * 64 + sl];
#pragma unroll
            for (int i = 0; i < 4; ++i)
#pragma unroll
                for (int j = 0; j < 4; ++j)
                    acc[i][j] = __builtin_amdgcn_mfma_f32_16x16x32_f16(af[i], bf[j], acc[i][j], 0, 0, 0);
        }
        __syncthreads();
    }

    // epilogue: C/D layout col = lane&15, row = quad*4 + reg  [m89/m91]
#pragma unroll
    for (int i = 0; i < 4; ++i) {
        long rbase = m0 + wm + i * 16 + quad * 4;
#pragma unroll
        for (int j = 0; j < 4; ++j) {
            long col = n0 + wn + j * 16 + lr;
#pragma unroll
            for (int r = 0; r < 4; ++r) {
                float val = acc[i][j][r] * scale;
                if (OUT_MODE == 0) {
                    ((_Float16*)C)[(rbase + r) * (long)N + col] = (_Float16)val;
                } else {
                    __hip_atomic_fetch_add(&((float*)C)[(rbase + r) * (long)N + col],
                                           val, __ATOMIC_RELAXED,
                                           __HIP_MEMORY_SCOPE_AGENT);
                }
            }
        }
    }
}

// ---------------- masked softmax, in-place on f16 logits [Q=4096][N=8192] ----------------
// Round-0 proven version: coalesced int4 mask loads + half4 logit loads; this
// pass moves 268 MB (mask 134 + logits r67+w67) and runs at its HBM roofline.
__global__ __launch_bounds__(256) void k_softmax(_Float16* __restrict__ logits,
                                                 const int* __restrict__ mask) {
    const int q   = blockIdx.x;
    const int tid = threadIdx.x;
    _Float16* row   = logits + (size_t)q * 8192;
    const int* mrow = mask + (size_t)q * 8192;

    float v[32];
    unsigned mb = 0;
    float lmax = -3.0e38f;
#pragma unroll
    for (int i = 0; i < 8; ++i) {
        int base = i * 1024 + tid * 4;
        int4 mm  = *(const int4*)(mrow + base);
        half4v h = *(const half4v*)(row + base);
#pragma unroll
        for (int j = 0; j < 4; ++j) v[i * 4 + j] = (float)h[j];
        if (mm.x > 0) { mb |= 1u << (i * 4 + 0); lmax = fmaxf(lmax, v[i * 4 + 0]); }
        if (mm.y > 0) { mb |= 1u << (i * 4 + 1); lmax = fmaxf(lmax, v[i * 4 + 1]); }
        if (mm.z > 0) { mb |= 1u << (i * 4 + 2); lmax = fmaxf(lmax, v[i * 4 + 2]); }
        if (mm.w > 0) { mb |= 1u << (i * 4 + 3); lmax = fmaxf(lmax, v[i * 4 + 3]); }
    }
#pragma unroll
    for (int off = 32; off > 0; off >>= 1) lmax = fmaxf(lmax, __shfl_xor(lmax, off, 64));
    __shared__ float redmax[4], redsum[4];
    if ((tid & 63) == 0) redmax[tid >> 6] = lmax;
    __syncthreads();
    lmax = fmaxf(fmaxf(redmax[0], redmax[1]), fmaxf(redmax[2], redmax[3]));

    float lsum = 0.f;
#pragma unroll
    for (int i = 0; i < 32; ++i) {
        float e = ((mb >> i) & 1u) ? __expf(v[i] - lmax) : 0.f;
        v[i] = e;
        lsum += e;
    }
#pragma unroll
    for (int off = 32; off > 0; off >>= 1) lsum += __shfl_xor(lsum, off, 64);
    if ((tid & 63) == 0) redsum[tid >> 6] = lsum;
    __syncthreads();
    lsum = redsum[0] + redsum[1] + redsum[2] + redsum[3];
    float inv = lsum > 0.f ? 1.f / lsum : 0.f;

#pragma unroll
    for (int i = 0; i < 8; ++i) {
        int base = i * 1024 + tid * 4;
        half4v h;
#pragma unroll
        for (int j = 0; j < 4; ++j) h[j] = (_Float16)(v[i * 4 + j] * inv);
        *(half4v*)(row + base) = h;
    }
}

extern "C" void kernel_launch(void* const* d_in, const int* in_sizes, int n_in,
                              void* d_out, int out_size, void* d_ws, size_t ws_size,
                              hipStream_t stream) {
    const float* search_x = (const float*)d_in[0];  // [8192,1024]
    const float* search_y = (const float*)d_in[1];  // [8192,256]
    const float* query_x  = (const float*)d_in[2];  // [4096,1024]
    const int*   mask     = (const int*)d_in[3];    // [4096,8192]
    const float* Wk       = (const float*)d_in[4];  // [1024,512]
    const float* Wq       = (const float*)d_in[5];  // [1024,512]
    (void)in_sizes; (void)n_in; (void)ws_size; (void)out_size;

    char* p = (char*)d_ws;
    _Float16* xh   = (_Float16*)p; p += (size_t)8192 * 1024 * 2;  // x f16
    _Float16* qh   = (_Float16*)p; p += (size_t)4096 * 1024 * 2;  // q f16
    _Float16* wkT  = (_Float16*)p; p += (size_t)512 * 1024 * 2;   // Wk^T f16 [512,1024]
    _Float16* wqT  = (_Float16*)p; p += (size_t)512 * 1024 * 2;   // Wq^T f16
    _Float16* yT   = (_Float16*)p; p += (size_t)256 * 8192 * 2;   // y^T f16 [256,8192]
    _Float16* keys = (_Float16*)p; p += (size_t)8192 * 512 * 2;   // keys f16 [8192,512]
    _Float16* qk   = (_Float16*)p; p += (size_t)4096 * 512 * 2;   // qk f16 [4096,512]
    _Float16* lg   = (_Float16*)p; p += (size_t)4096 * 8192 * 2;  // logits/p f16

    // converts + transposes
    k_f32_to_f16_2<<<12288, 256, 0, stream>>>(search_x, xh, 8192 * 1024,
                                              query_x, qh, 4096 * 1024);
    k_transpose_f16<<<dim3(16, 32), 256, 0, stream>>>(Wk, wkT, 1024, 512);
    k_transpose_f16<<<dim3(16, 32), 256, 0, stream>>>(Wq, wqT, 1024, 512);
    k_transpose_f16<<<dim3(8, 256), 256, 0, stream>>>(search_y, yT, 8192, 256);
    // zero the output for atomic split-K accumulation
    k_zero_f32<<<1024, 256, 0, stream>>>((float*)d_out, 4096 * 256);

    // keys = x @ Wk   (M=8192,N=512,K=1024)
    k_gemm_nt<0><<<dim3(4, 64, 1), 256, 0, stream>>>(xh, wkT, keys, 8192, 512, 1024, 1024, 1.0f);
    // qk = q @ Wq     (M=4096,N=512,K=1024)
    k_gemm_nt<0><<<dim3(4, 32, 1), 256, 0, stream>>>(qh, wqT, qk, 4096, 512, 1024, 1024, 1.0f);
    // logits = (qk @ keys^T) / sqrt(512)   (M=4096,N=8192,K=512)
    k_gemm_nt<0><<<dim3(64, 32, 1), 256, 0, stream>>>(qk, keys, lg, 4096, 8192, 512, 512,
                                                      0.04419417382415922f);
    // masked softmax in-place
    k_softmax<<<4096, 256, 0, stream>>>(lg, mask);
    // out = p @ y     (M=4096,N=256,K=8192), split-K=4, f32 atomics into d_out
    k_gemm_nt<1><<<dim3(2, 32, 4), 256, 0, stream>>>(lg, yT, (float*)d_out,
                                                     4096, 256, 8192, 2048, 1.0f);
}

// Round 4
// 389.946 us; speedup vs baseline: 1.2302x; 1.0055x over previous
//
#include <hip/hip_runtime.h>
#include <hip/hip_fp16.h>

typedef _Float16 half4v __attribute__((ext_vector_type(4)));
typedef _Float16 half8v __attribute__((ext_vector_type(8)));
typedef float floatx4 __attribute__((ext_vector_type(4)));

#define GLOBAL_AS __attribute__((address_space(1)))
#define LDS_AS __attribute__((address_space(3)))

// async 16B/lane global->LDS DMA; lds dest = wave-uniform base + lane*16
__device__ __forceinline__ void async_copy16(const _Float16* g, _Float16* l) {
    __builtin_amdgcn_global_load_lds((const GLOBAL_AS unsigned int*)g,
                                     (LDS_AS unsigned int*)l, 16, 0, 0);
}

// ---------------- convert f32 -> f16, two tensors in one launch ----------------
__global__ __launch_bounds__(256) void k_f32_to_f16_2(const float* __restrict__ a,
                                                      _Float16* __restrict__ oa, int na,
                                                      const float* __restrict__ b,
                                                      _Float16* __restrict__ ob, int nb) {
    int i = (blockIdx.x * 256 + threadIdx.x) * 4;
    const float* src;
    _Float16* dst;
    if (i < na) {
        src = a + i; dst = oa + i;
    } else {
        int j = i - na;
        if (j >= nb) return;
        src = b + j; dst = ob + j;
    }
    float4 v = *(const float4*)src;
    half4v h;
    h[0] = (_Float16)v.x; h[1] = (_Float16)v.y; h[2] = (_Float16)v.z; h[3] = (_Float16)v.w;
    *(half4v*)dst = h;
}

// ------------- transpose + convert: in[R][C] f32 -> out[C][R] f16 -------------
__global__ __launch_bounds__(256) void k_transpose_f16(const float* __restrict__ in,
                                                       _Float16* __restrict__ out,
                                                       int R, int C) {
    __shared__ float tile[32][33];
    int bc = blockIdx.x * 32;
    int br = blockIdx.y * 32;
    int tx = threadIdx.x & 31, ty = threadIdx.x >> 5;  // 32x8
#pragma unroll
    for (int i = 0; i < 32; i += 8)
        tile[ty + i][tx] = in[(size_t)(br + ty + i) * C + bc + tx];
    __syncthreads();
#pragma unroll
    for (int i = 0; i < 32; i += 8)
        out[(size_t)(bc + ty + i) * R + br + tx] = (_Float16)tile[tx][ty + i];
}

// ---------------- NT GEMM: C[M,N] = scale * A[M,K] @ B[N,K]^T ----------------
// 128x128 tile, BK=64, 256 threads = 4 waves (2x2 of 64x64), mfma_f32_16x16x32_f16.
// global_load_lds width=16 staging; XOR chunk swizzle (LDS slot (row,c) holds
// global chunk (row, c^(row&7))) kills fragment-read bank conflicts (proven,
// SQ_LDS_BANK_CONFLICT==0 in prior rounds).
// OUT_MODE 0: f16 store (scaled).
// OUT_MODE 1: f32 partial store at C + blockIdx.z*M*N (split-K; reduced later).
// OUT_MODE 2: f16 store with fused mask -> -inf at masked positions. Mask tile
//   (128x128 int32, 64 KB) is loaded COOPERATIVELY COALESCED (int4/lane) after
//   the K-loop, packed to nibbles in 4 KB LDS, and the epilogue reads bits from
//   LDS. This fixes round-1's +50us regression (scalar fragment-order mask
//   reads) while keeping softmax mask-free (-134 MB there).
template <int OUT_MODE>
__global__ __launch_bounds__(256) void k_gemm_nt(const _Float16* __restrict__ A,
                                                 const _Float16* __restrict__ B,
                                                 void* __restrict__ C,
                                                 const int* __restrict__ Mask,
                                                 int M, int N, int K, int kChunk,
                                                 float scale) {
    __shared__ __align__(16) _Float16 As[128 * 64];
    __shared__ __align__(16) _Float16 Bs[128 * 64];
    const int tid  = threadIdx.x;
    const int lane = tid & 63;
    const int wave = tid >> 6;
    const int wm   = (wave >> 1) * 64;
    const int wn   = (wave & 1) * 64;
    const int quad = lane >> 4;
    const int lr   = lane & 15;
    const long m0 = (long)blockIdx.y * 128;
    const long n0 = (long)blockIdx.x * 128;
    const int kBegin = blockIdx.z * kChunk;
    const int kEnd   = kBegin + kChunk;

    floatx4 acc[4][4] = {};

    // stager geometry (per lane, i-independent)
    const int rl = lane >> 3;                       // row offset within 8-row group
    const int gc = (lane & 7) ^ rl;                 // swizzled global chunk
    const long arow = m0 + wave * 32 + rl;          // + i*8
    const long brow = n0 + wave * 32 + rl;

    for (int kt = kBegin; kt < kEnd; kt += 64) {
        const _Float16* Ap = A + arow * (long)K + kt + gc * 8;
        const _Float16* Bp = B + brow * (long)K + kt + gc * 8;
        _Float16* Al = &As[(wave * 32) * 64];
        _Float16* Bl = &Bs[(wave * 32) * 64];
#pragma unroll
        for (int i = 0; i < 4; ++i) {
            async_copy16(Ap + (long)(i * 8) * K, Al + i * 8 * 64);
            async_copy16(Bp + (long)(i * 8) * K, Bl + i * 8 * 64);
        }
        __syncthreads();  // compiler inserts vmcnt(0) drain before barrier

#pragma unroll
        for (int kk = 0; kk < 64; kk += 32) {
            half8v af[4], bf[4];
            const int cg = (kk >> 3) + quad;        // global chunk index 0..7
            const int sl = (cg ^ (lr & 7)) * 8;     // swizzled slot offset (halves)
#pragma unroll
            for (int i = 0; i < 4; ++i)
                af[i] = *(const half8v*)&As[(wm + i * 16 + lr) * 64 + sl];
#pragma unroll
            for (int j = 0; j < 4; ++j)
                bf[j] = *(const half8v*)&Bs[(wn + j * 16 + lr) * 64 + sl];
#pragma unroll
            for (int i = 0; i < 4; ++i)
#pragma unroll
                for (int j = 0; j < 4; ++j)
                    acc[i][j] = __builtin_amdgcn_mfma_f32_16x16x32_f16(af[i], bf[j], acc[i][j], 0, 0, 0);
        }
        __syncthreads();
    }

    if constexpr (OUT_MODE == 2) {
        // coalesced mask-tile load + nibble pack: mnib[r][l] holds bits for
        // cols 4l..4l+3 of tile row r.
        __shared__ unsigned char mnib[128][32];
#pragma unroll
        for (int p = 0; p < 16; ++p) {
            const int rloc = p * 8 + (tid >> 5);
            const int4 mm = *(const int4*)(Mask + (m0 + rloc) * (long)N + n0 + (tid & 31) * 4);
            mnib[rloc][tid & 31] =
                (unsigned char)((mm.x > 0) | ((mm.y > 0) << 1) |
                                ((mm.z > 0) << 2) | ((mm.w > 0) << 3));
        }
        __syncthreads();

#pragma unroll
        for (int i = 0; i < 4; ++i) {
            const int rloc0 = wm + i * 16 + quad * 4;
            const long rbase = m0 + rloc0;
#pragma unroll
            for (int j = 0; j < 4; ++j) {
                const int cl = wn + j * 16 + lr;     // tile-local col
                const long col = n0 + cl;
#pragma unroll
                for (int r = 0; r < 4; ++r) {
                    const unsigned bit = (mnib[rloc0 + r][cl >> 2] >> (cl & 3)) & 1u;
                    const float val = acc[i][j][r] * scale;
                    ((_Float16*)C)[(rbase + r) * (long)N + col] =
                        bit ? (_Float16)val : (_Float16)(-__builtin_huge_valf());
                }
            }
        }
        return;
    }

    // epilogue modes 0/1: C/D layout col = lane&15, row = quad*4 + reg  [m89/m91]
#pragma unroll
    for (int i = 0; i < 4; ++i) {
        long rbase = m0 + wm + i * 16 + quad * 4;
#pragma unroll
        for (int j = 0; j < 4; ++j) {
            long col = n0 + wn + j * 16 + lr;
#pragma unroll
            for (int r = 0; r < 4; ++r) {
                float val = acc[i][j][r] * scale;
                if (OUT_MODE == 0)
                    ((_Float16*)C)[(rbase + r) * (long)N + col] = (_Float16)val;
                else
                    ((float*)C)[(size_t)blockIdx.z * M * N + (rbase + r) * (long)N + col] = val;
            }
        }
    }
}

// ---------------- sum Z fp32 partials [Z][n] -> out[n] (n multiple of 4) ----------------
template <int Z>
__global__ __launch_bounds__(256) void k_reduce(const float* __restrict__ part,
                                                float* __restrict__ out, int n) {
    int i = (blockIdx.x * 256 + threadIdx.x) * 4;
    if (i >= n) return;
    float4 s = *(const float4*)(part + i);
#pragma unroll
    for (int z = 1; z < Z; ++z) {
        float4 v = *(const float4*)(part + (size_t)z * n + i);
        s.x += v.x; s.y += v.y; s.z += v.z; s.w += v.w;
    }
    *(float4*)(out + i) = s;
}

// ---------------- softmax, in-place on pre-masked f16 logits [Q=4096][N=8192] -------
// Masked positions hold -inf (written by the logits GEMM epilogue), so
// exp(v - max) is exactly 0 there: masked-softmax semantics with no mask
// traffic here. All-masked rows: lsum==0 -> inv=0 -> zeros (matches reference).
__global__ __launch_bounds__(256) void k_softmax(_Float16* __restrict__ logits) {
    const int q   = blockIdx.x;
    const int tid = threadIdx.x;
    _Float16* row = logits + (size_t)q * 8192;

    float v[32];
    float lmax = -3.0e38f;
#pragma unroll
    for (int i = 0; i < 4; ++i) {
        int base = i * 2048 + tid * 8;
        half8v h = *(const half8v*)(row + base);
#pragma unroll
        for (int j = 0; j < 8; ++j) {
            v[i * 8 + j] = (float)h[j];
            lmax = fmaxf(lmax, v[i * 8 + j]);
        }
    }
#pragma unroll
    for (int off = 32; off > 0; off >>= 1) lmax = fmaxf(lmax, __shfl_xor(lmax, off, 64));
    __shared__ float redmax[4], redsum[4];
    if ((tid & 63) == 0) redmax[tid >> 6] = lmax;
    __syncthreads();
    lmax = fmaxf(fmaxf(redmax[0], redmax[1]), fmaxf(redmax[2], redmax[3]));

    float lsum = 0.f;
#pragma unroll
    for (int i = 0; i < 32; ++i) {
        float e = __expf(v[i] - lmax);  // -inf -> 0
        v[i] = e;
        lsum += e;
    }
#pragma unroll
    for (int off = 32; off > 0; off >>= 1) lsum += __shfl_xor(lsum, off, 64);
    if ((tid & 63) == 0) redsum[tid >> 6] = lsum;
    __syncthreads();
    lsum = redsum[0] + redsum[1] + redsum[2] + redsum[3];
    float inv = lsum > 0.f ? 1.f / lsum : 0.f;

#pragma unroll
    for (int i = 0; i < 4; ++i) {
        int base = i * 2048 + tid * 8;
        half8v h;
#pragma unroll
        for (int j = 0; j < 8; ++j) h[j] = (_Float16)(v[i * 8 + j] * inv);
        *(half8v*)(row + base) = h;
    }
}

extern "C" void kernel_launch(void* const* d_in, const int* in_sizes, int n_in,
                              void* d_out, int out_size, void* d_ws, size_t ws_size,
                              hipStream_t stream) {
    const float* search_x = (const float*)d_in[0];  // [8192,1024]
    const float* search_y = (const float*)d_in[1];  // [8192,256]
    const float* query_x  = (const float*)d_in[2];  // [4096,1024]
    const int*   mask     = (const int*)d_in[3];    // [4096,8192]
    const float* Wk       = (const float*)d_in[4];  // [1024,512]
    const float* Wq       = (const float*)d_in[5];  // [1024,512]
    (void)in_sizes; (void)n_in; (void)ws_size; (void)out_size;

    char* p = (char*)d_ws;
    _Float16* xh   = (_Float16*)p; p += (size_t)8192 * 1024 * 2;  // x f16
    _Float16* qh   = (_Float16*)p; p += (size_t)4096 * 1024 * 2;  // q f16
    _Float16* wkT  = (_Float16*)p; p += (size_t)512 * 1024 * 2;   // Wk^T f16 [512,1024]
    _Float16* wqT  = (_Float16*)p; p += (size_t)512 * 1024 * 2;   // Wq^T f16
    _Float16* yT   = (_Float16*)p; p += (size_t)256 * 8192 * 2;   // y^T f16 [256,8192]
    _Float16* keys = (_Float16*)p; p += (size_t)8192 * 512 * 2;   // keys f16 [8192,512]
    _Float16* qk   = (_Float16*)p; p += (size_t)4096 * 512 * 2;   // qk f16 [4096,512]
    _Float16* lg   = (_Float16*)p; p += (size_t)4096 * 8192 * 2;  // logits/p f16
    float*    part = (float*)p;    p += (size_t)4 * 4096 * 256 * 4; // PV split-K partials

    // converts + transposes
    k_f32_to_f16_2<<<12288, 256, 0, stream>>>(search_x, xh, 8192 * 1024,
                                              query_x, qh, 4096 * 1024);
    k_transpose_f16<<<dim3(16, 32), 256, 0, stream>>>(Wk, wkT, 1024, 512);
    k_transpose_f16<<<dim3(16, 32), 256, 0, stream>>>(Wq, wqT, 1024, 512);
    k_transpose_f16<<<dim3(8, 256), 256, 0, stream>>>(search_y, yT, 8192, 256);

    // keys = x @ Wk   (M=8192,N=512,K=1024)
    k_gemm_nt<0><<<dim3(4, 64, 1), 256, 0, stream>>>(xh, wkT, keys, nullptr,
                                                     8192, 512, 1024, 1024, 1.0f);
    // qk = q @ Wq     (M=4096,N=512,K=1024)
    k_gemm_nt<0><<<dim3(4, 32, 1), 256, 0, stream>>>(qh, wqT, qk, nullptr,
                                                     4096, 512, 1024, 1024, 1.0f);
    // logits = (qk @ keys^T) / sqrt(512), fused coalesced mask -> -inf
    k_gemm_nt<2><<<dim3(64, 32, 1), 256, 0, stream>>>(qk, keys, lg, mask,
                                                      4096, 8192, 512, 512,
                                                      0.04419417382415922f);
    // softmax in-place (mask already folded into logits)
    k_softmax<<<4096, 256, 0, stream>>>(lg);
    // out = p @ y     (M=4096,N=256,K=8192), split-K=4 -> fp32 partials, reduce
    k_gemm_nt<1><<<dim3(2, 32, 4), 256, 0, stream>>>(lg, yT, part, nullptr,
                                                     4096, 256, 8192, 2048, 1.0f);
    k_reduce<4><<<1024, 256, 0, stream>>>(part, (float*)d_out, 4096 * 256);
}

// Round 5
// 353.552 us; speedup vs baseline: 1.3568x; 1.1029x over previous
//
#include <hip/hip_runtime.h>
#include <hip/hip_fp16.h>

typedef _Float16 half4v __attribute__((ext_vector_type(4)));
typedef _Float16 half8v __attribute__((ext_vector_type(8)));
typedef float floatx4 __attribute__((ext_vector_type(4)));

#define GLOBAL_AS __attribute__((address_space(1)))
#define LDS_AS __attribute__((address_space(3)))

// async 16B/lane global->LDS DMA; lds dest = wave-uniform base + lane*16
__device__ __forceinline__ void async_copy16(const _Float16* g, _Float16* l) {
    __builtin_amdgcn_global_load_lds((const GLOBAL_AS unsigned int*)g,
                                     (LDS_AS unsigned int*)l, 16, 0, 0);
}

// ---------------- fused preprocessing: converts + 3 transposes, one launch --------
// blocks [0,12288):      f32->f16 convert of x (8.4M) then q (4.2M), 1024 elems/blk
// blocks [12288,12800):  Wk [1024,512] -> wkT [512,1024]
// blocks [12800,13312):  Wq -> wqT
// blocks [13312,15360):  y  [8192,256] -> yT [256,8192]
__device__ __forceinline__ void transpose_tile(const float* __restrict__ in,
                                               _Float16* __restrict__ out,
                                               int R, int C, int bx, int by,
                                               float* tile /*[32][33]*/) {
    int tx = threadIdx.x & 31, ty = threadIdx.x >> 5;  // 32x8
    int bc = bx * 32, br = by * 32;
#pragma unroll
    for (int i = 0; i < 32; i += 8)
        tile[(ty + i) * 33 + tx] = in[(size_t)(br + ty + i) * C + bc + tx];
    __syncthreads();
#pragma unroll
    for (int i = 0; i < 32; i += 8)
        out[(size_t)(bc + ty + i) * R + br + tx] = (_Float16)tile[tx * 33 + ty + i];
}

__global__ __launch_bounds__(256) void k_preproc(const float* __restrict__ x,
                                                 _Float16* __restrict__ xh,
                                                 const float* __restrict__ q,
                                                 _Float16* __restrict__ qh,
                                                 const float* __restrict__ Wk,
                                                 _Float16* __restrict__ wkT,
                                                 const float* __restrict__ Wq,
                                                 _Float16* __restrict__ wqT,
                                                 const float* __restrict__ y,
                                                 _Float16* __restrict__ yT) {
    __shared__ float tile[32 * 33];
    const int b = blockIdx.x;
    if (b < 12288) {
        const int na = 8192 * 1024;            // divisible by 4
        int i = (b * 256 + threadIdx.x) * 4;   // [0, 12582912)
        const float* src;
        _Float16* dst;
        if (i < na) { src = x + i; dst = xh + i; }
        else        { src = q + (i - na); dst = qh + (i - na); }
        float4 v = *(const float4*)src;
        half4v h;
        h[0] = (_Float16)v.x; h[1] = (_Float16)v.y;
        h[2] = (_Float16)v.z; h[3] = (_Float16)v.w;
        *(half4v*)dst = h;
    } else if (b < 12800) {
        const int idx = b - 12288;             // Wk: C/32=16, R/32=32
        transpose_tile(Wk, wkT, 1024, 512, idx & 15, idx >> 4, tile);
    } else if (b < 13312) {
        const int idx = b - 12800;
        transpose_tile(Wq, wqT, 1024, 512, idx & 15, idx >> 4, tile);
    } else {
        const int idx = b - 13312;             // y: C/32=8, R/32=256
        transpose_tile(y, yT, 8192, 256, idx & 7, idx >> 3, tile);
    }
}

// ---------------- NT GEMM: C[M,N] = scale * A[M,K] @ B[N,K]^T ----------------
// 128x128 tile, BK=64, 256 threads = 4 waves (2x2 of 64x64), mfma_f32_16x16x32_f16.
// global_load_lds width=16 staging; XOR chunk swizzle (LDS slot (row,c) holds
// global chunk (row, c^(row&7))) kills fragment-read bank conflicts (proven,
// SQ_LDS_BANK_CONFLICT==0).
// OUT_MODE 0: f16 store (scaled).
// OUT_MODE 1: f32 partial store at C + blockIdx.z*M*N (split-K; reduced later).
// OUT_MODE 3: merged projections -- blockIdx.y < 64 computes (A,B,C,scale),
//             blockIdx.y >= 64 computes (A2,B2,C2,scale2). Same N,K for both.
template <int OUT_MODE>
__global__ __launch_bounds__(256) void k_gemm_nt(const _Float16* __restrict__ A,
                                                 const _Float16* __restrict__ B,
                                                 void* __restrict__ C,
                                                 const _Float16* __restrict__ A2,
                                                 const _Float16* __restrict__ B2,
                                                 void* __restrict__ C2,
                                                 int M, int N, int K, int kChunk,
                                                 float scale, float scale2) {
    __shared__ __align__(16) _Float16 As[128 * 64];
    __shared__ __align__(16) _Float16 Bs[128 * 64];
    const int tid  = threadIdx.x;
    const int lane = tid & 63;
    const int wave = tid >> 6;
    const int wm   = (wave >> 1) * 64;
    const int wn   = (wave & 1) * 64;
    const int quad = lane >> 4;
    const int lr   = lane & 15;

    int by = blockIdx.y;
    if (OUT_MODE == 3 && by >= 64) {
        by -= 64;
        A = A2; B = B2; C = C2; scale = scale2;
    }
    const long m0 = (long)by * 128;
    const long n0 = (long)blockIdx.x * 128;
    const int kBegin = blockIdx.z * kChunk;
    const int kEnd   = kBegin + kChunk;

    floatx4 acc[4][4] = {};

    // stager geometry (per lane, i-independent)
    const int rl = lane >> 3;                       // row offset within 8-row group
    const int gc = (lane & 7) ^ rl;                 // swizzled global chunk
    const long arow = m0 + wave * 32 + rl;          // + i*8
    const long brow = n0 + wave * 32 + rl;

    for (int kt = kBegin; kt < kEnd; kt += 64) {
        const _Float16* Ap = A + arow * (long)K + kt + gc * 8;
        const _Float16* Bp = B + brow * (long)K + kt + gc * 8;
        _Float16* Al = &As[(wave * 32) * 64];
        _Float16* Bl = &Bs[(wave * 32) * 64];
#pragma unroll
        for (int i = 0; i < 4; ++i) {
            async_copy16(Ap + (long)(i * 8) * K, Al + i * 8 * 64);
            async_copy16(Bp + (long)(i * 8) * K, Bl + i * 8 * 64);
        }
        __syncthreads();  // compiler inserts vmcnt(0) drain before barrier

#pragma unroll
        for (int kk = 0; kk < 64; kk += 32) {
            half8v af[4], bf[4];
            const int cg = (kk >> 3) + quad;        // global chunk index 0..7
            const int sl = (cg ^ (lr & 7)) * 8;     // swizzled slot offset (halves)
#pragma unroll
            for (int i = 0; i < 4; ++i)
                af[i] = *(const half8v*)&As[(wm + i * 16 + lr) * 64 + sl];
#pragma unroll
            for (int j = 0; j < 4; ++j)
                bf[j] = *(const half8v*)&Bs[(wn + j * 16 + lr) * 64 + sl];
#pragma unroll
            for (int i = 0; i < 4; ++i)
#pragma unroll
                for (int j = 0; j < 4; ++j)
                    acc[i][j] = __builtin_amdgcn_mfma_f32_16x16x32_f16(af[i], bf[j], acc[i][j], 0, 0, 0);
        }
        __syncthreads();
    }

    // epilogue: C/D layout col = lane&15, row = quad*4 + reg  [m89/m91]
#pragma unroll
    for (int i = 0; i < 4; ++i) {
        long rbase = m0 + wm + i * 16 + quad * 4;
#pragma unroll
        for (int j = 0; j < 4; ++j) {
            long col = n0 + wn + j * 16 + lr;
#pragma unroll
            for (int r = 0; r < 4; ++r) {
                float val = acc[i][j][r] * scale;
                if (OUT_MODE == 1)
                    ((float*)C)[(size_t)blockIdx.z * M * N + (rbase + r) * (long)N + col] = val;
                else
                    ((_Float16*)C)[(rbase + r) * (long)N + col] = (_Float16)val;
            }
        }
    }
}

// ---------------- sum Z fp32 partials [Z][n] -> out[n] (n multiple of 4) ----------------
template <int Z>
__global__ __launch_bounds__(256) void k_reduce(const float* __restrict__ part,
                                                float* __restrict__ out, int n) {
    int i = (blockIdx.x * 256 + threadIdx.x) * 4;
    if (i >= n) return;
    float4 s = *(const float4*)(part + i);
#pragma unroll
    for (int z = 1; z < Z; ++z) {
        float4 v = *(const float4*)(part + (size_t)z * n + i);
        s.x += v.x; s.y += v.y; s.z += v.z; s.w += v.w;
    }
    *(float4*)(out + i) = s;
}

// ---------------- masked softmax, in-place on f16 logits [Q=4096][N=8192] ----------------
// Round-0 proven version: coalesced int4 mask loads + half4 logit loads; this
// pass moves 268 MB (mask 134 + logits r67+w67) and runs at its HBM roofline.
__global__ __launch_bounds__(256) void k_softmax(_Float16* __restrict__ logits,
                                                 const int* __restrict__ mask) {
    const int q   = blockIdx.x;
    const int tid = threadIdx.x;
    _Float16* row   = logits + (size_t)q * 8192;
    const int* mrow = mask + (size_t)q * 8192;

    float v[32];
    unsigned mb = 0;
    float lmax = -3.0e38f;
#pragma unroll
    for (int i = 0; i < 8; ++i) {
        int base = i * 1024 + tid * 4;
        int4 mm  = *(const int4*)(mrow + base);
        half4v h = *(const half4v*)(row + base);
#pragma unroll
        for (int j = 0; j < 4; ++j) v[i * 4 + j] = (float)h[j];
        if (mm.x > 0) { mb |= 1u << (i * 4 + 0); lmax = fmaxf(lmax, v[i * 4 + 0]); }
        if (mm.y > 0) { mb |= 1u << (i * 4 + 1); lmax = fmaxf(lmax, v[i * 4 + 1]); }
        if (mm.z > 0) { mb |= 1u << (i * 4 + 2); lmax = fmaxf(lmax, v[i * 4 + 2]); }
        if (mm.w > 0) { mb |= 1u << (i * 4 + 3); lmax = fmaxf(lmax, v[i * 4 + 3]); }
    }
#pragma unroll
    for (int off = 32; off > 0; off >>= 1) lmax = fmaxf(lmax, __shfl_xor(lmax, off, 64));
    __shared__ float redmax[4], redsum[4];
    if ((tid & 63) == 0) redmax[tid >> 6] = lmax;
    __syncthreads();
    lmax = fmaxf(fmaxf(redmax[0], redmax[1]), fmaxf(redmax[2], redmax[3]));

    float lsum = 0.f;
#pragma unroll
    for (int i = 0; i < 32; ++i) {
        float e = ((mb >> i) & 1u) ? __expf(v[i] - lmax) : 0.f;
        v[i] = e;
        lsum += e;
    }
#pragma unroll
    for (int off = 32; off > 0; off >>= 1) lsum += __shfl_xor(lsum, off, 64);
    if ((tid & 63) == 0) redsum[tid >> 6] = lsum;
    __syncthreads();
    lsum = redsum[0] + redsum[1] + redsum[2] + redsum[3];
    float inv = lsum > 0.f ? 1.f / lsum : 0.f;

#pragma unroll
    for (int i = 0; i < 8; ++i) {
        int base = i * 1024 + tid * 4;
        half4v h;
#pragma unroll
        for (int j = 0; j < 4; ++j) h[j] = (_Float16)(v[i * 4 + j] * inv);
        *(half4v*)(row + base) = h;
    }
}

extern "C" void kernel_launch(void* const* d_in, const int* in_sizes, int n_in,
                              void* d_out, int out_size, void* d_ws, size_t ws_size,
                              hipStream_t stream) {
    const float* search_x = (const float*)d_in[0];  // [8192,1024]
    const float* search_y = (const float*)d_in[1];  // [8192,256]
    const float* query_x  = (const float*)d_in[2];  // [4096,1024]
    const int*   mask     = (const int*)d_in[3];    // [4096,8192]
    const float* Wk       = (const float*)d_in[4];  // [1024,512]
    const float* Wq       = (const float*)d_in[5];  // [1024,512]
    (void)in_sizes; (void)n_in; (void)ws_size; (void)out_size;

    char* p = (char*)d_ws;
    _Float16* xh   = (_Float16*)p; p += (size_t)8192 * 1024 * 2;  // x f16
    _Float16* qh   = (_Float16*)p; p += (size_t)4096 * 1024 * 2;  // q f16
    _Float16* wkT  = (_Float16*)p; p += (size_t)512 * 1024 * 2;   // Wk^T f16 [512,1024]
    _Float16* wqT  = (_Float16*)p; p += (size_t)512 * 1024 * 2;   // Wq^T f16
    _Float16* yT   = (_Float16*)p; p += (size_t)256 * 8192 * 2;   // y^T f16 [256,8192]
    _Float16* keys = (_Float16*)p; p += (size_t)8192 * 512 * 2;   // keys f16 [8192,512]
    _Float16* qk   = (_Float16*)p; p += (size_t)4096 * 512 * 2;   // qk f16 (pre-scaled)
    _Float16* lg   = (_Float16*)p; p += (size_t)4096 * 8192 * 2;  // logits/p f16
    float*    part = (float*)p;    p += (size_t)4 * 4096 * 256 * 4; // PV split-K partials

    // all preprocessing in one launch
    k_preproc<<<15360, 256, 0, stream>>>(search_x, xh, query_x, qh,
                                         Wk, wkT, Wq, wqT, search_y, yT);

    // merged projections: keys = x @ Wk (by<64); qk = (q @ Wq)/sqrt(512) (by>=64)
    k_gemm_nt<3><<<dim3(4, 96, 1), 256, 0, stream>>>(
        xh, wkT, keys, qh, wqT, qk, 8192, 512, 1024, 1024,
        1.0f, 0.04419417382415922f);

    // logits = qk @ keys^T  (scale already folded into qk)
    k_gemm_nt<0><<<dim3(64, 32, 1), 256, 0, stream>>>(
        qk, keys, lg, nullptr, nullptr, nullptr, 4096, 8192, 512, 512, 1.0f, 0.f);

    // masked softmax in-place
    k_softmax<<<4096, 256, 0, stream>>>(lg, mask);

    // out = p @ y  (M=4096,N=256,K=8192), split-K=4 -> fp32 partials, reduce
    k_gemm_nt<1><<<dim3(2, 32, 4), 256, 0, stream>>>(
        lg, yT, part, nullptr, nullptr, nullptr, 4096, 256, 8192, 2048, 1.0f, 0.f);
    k_reduce<4><<<1024, 256, 0, stream>>>(part, (float*)d_out, 4096 * 256);
}